// Round 1
// baseline (21840.074 us; speedup 1.0000x reference)
//
#include <hip/hip_runtime.h>
#include <math.h>

#define T_STEPS 512
#define B_SZ    64
#define I_SZ    1024
#define H_SZ    1024
// N4 = 4*H = 4096

__device__ __forceinline__ float sigmoidf_(float x) { return 1.0f / (1.0f + expf(-x)); }

// ---------------------------------------------------------------------------
// Phase 1: wx[m][n] = X[m][k] @ W[k][n] + bias[n]   (M=32768, N=4096, K=1024)
// fp32 vector GEMM, BM=64 BN=128 BK=16, 256 thr, 4x8 per thread.
// ---------------------------------------------------------------------------
#define BM 64
#define BN 128
#define BK 16

__global__ __launch_bounds__(256)
void wx_gemm(const float* __restrict__ X, const float* __restrict__ W,
             const float* __restrict__ bias, float* __restrict__ wx)
{
    __shared__ float As[BK][BM + 4];   // [k][m], +4 pad keeps float4 alignment, 2-way banks
    __shared__ float Bs[BK][BN];       // [k][n]

    const int tid = threadIdx.x;
    const int tx  = tid & 15;          // n-dir, 16 threads
    const int ty  = tid >> 4;          // m-dir, 16 threads
    const int m0  = blockIdx.y * BM;
    const int n0  = blockIdx.x * BN;

    float acc[4][8] = {};

    // A staging: 64 rows x 16 k = 256 float4 -> 1 per thread
    const int arow = tid >> 2;
    const int ak   = (tid & 3) * 4;
    // B staging: 16 rows x 128 cols = 512 float4 -> 2 per thread (rows brow, brow+8)
    const int brow = tid >> 5;
    const int bcol = (tid & 31) * 4;

    const float* Ag = X + (size_t)(m0 + arow) * I_SZ + ak;
    const float* Bg = W + (size_t)brow * 4096 + n0 + bcol;

    for (int k0 = 0; k0 < I_SZ; k0 += BK) {
        float4 av  = *(const float4*)(Ag + k0);
        float4 bv0 = *(const float4*)(Bg + (size_t)k0 * 4096);
        float4 bv1 = *(const float4*)(Bg + (size_t)(k0 + 8) * 4096);
        __syncthreads();   // protect previous iteration's LDS reads
        As[ak + 0][arow] = av.x;
        As[ak + 1][arow] = av.y;
        As[ak + 2][arow] = av.z;
        As[ak + 3][arow] = av.w;
        *(float4*)&Bs[brow][bcol]     = bv0;
        *(float4*)&Bs[brow + 8][bcol] = bv1;
        __syncthreads();
        #pragma unroll
        for (int kk = 0; kk < BK; ++kk) {
            float4 a  = *(const float4*)&As[kk][ty * 4];
            float4 b0 = *(const float4*)&Bs[kk][tx * 8];
            float4 b1 = *(const float4*)&Bs[kk][tx * 8 + 4];
            float aa[4] = {a.x, a.y, a.z, a.w};
            float bb[8] = {b0.x, b0.y, b0.z, b0.w, b1.x, b1.y, b1.z, b1.w};
            #pragma unroll
            for (int i = 0; i < 4; ++i)
                #pragma unroll
                for (int jn = 0; jn < 8; ++jn)
                    acc[i][jn] = fmaf(aa[i], bb[jn], acc[i][jn]);
        }
    }

    float4 bi0 = *(const float4*)(bias + n0 + tx * 8);
    float4 bi1 = *(const float4*)(bias + n0 + tx * 8 + 4);
    float bb[8] = {bi0.x, bi0.y, bi0.z, bi0.w, bi1.x, bi1.y, bi1.z, bi1.w};
    #pragma unroll
    for (int i = 0; i < 4; ++i) {
        float* orow = wx + (size_t)(m0 + ty * 4 + i) * 4096 + n0 + tx * 8;
        float4 s0 = make_float4(acc[i][0] + bb[0], acc[i][1] + bb[1],
                                acc[i][2] + bb[2], acc[i][3] + bb[3]);
        float4 s1 = make_float4(acc[i][4] + bb[4], acc[i][5] + bb[5],
                                acc[i][6] + bb[6], acc[i][7] + bb[7]);
        *(float4*)orow       = s0;
        *(float4*)(orow + 4) = s1;
    }
}

// ---------------------------------------------------------------------------
// Phase 2: one kernel per timestep.
// Block: 4 h-columns (j0..j0+3) x 4 gates x all 64 batches. Grid = 256 blocks.
// Thread: (b = tid&63, jj = tid>>6) -> one (b,j) pair, 4 gate accumulators.
// K tiled by 64 through LDS. vs[k][b] (pad 66 -> 2-way banks),
// ms[k][jj*4+g] (row stride 20 keeps float4 alignment).
// ---------------------------------------------------------------------------
__device__ __forceinline__ void accum_tile(
    const float* __restrict__ vec,   // [64][1024] row-major (h_prev or x_t)
    const float* __restrict__ mat,   // [1024][4096] (R or W)
    int j0, int tid, int b, int jj,
    float (&vs)[64][66], float (&ms)[64][20],
    float& a0, float& a1, float& a2, float& a3)
{
    const int lb  = tid & 63;        // vec row to stage
    const int lkq = tid >> 6;        // which 16-k chunk
    const int rk  = tid & 63;        // mat row to stage
    const int rg  = tid >> 6;        // gate

    const float* Vg = vec + (size_t)lb * 1024 + lkq * 16;
    const float* Mg = mat + (size_t)rk * 4096 + (size_t)rg * 1024 + j0;

    for (int k0 = 0; k0 < 1024; k0 += 64) {
        float4 v0 = *(const float4*)(Vg + k0 + 0);
        float4 v1 = *(const float4*)(Vg + k0 + 4);
        float4 v2 = *(const float4*)(Vg + k0 + 8);
        float4 v3 = *(const float4*)(Vg + k0 + 12);
        float4 mv = *(const float4*)(Mg + (size_t)k0 * 4096);
        __syncthreads();   // protect previous tile's reads
        const int kb = lkq * 16;
        vs[kb +  0][lb] = v0.x; vs[kb +  1][lb] = v0.y;
        vs[kb +  2][lb] = v0.z; vs[kb +  3][lb] = v0.w;
        vs[kb +  4][lb] = v1.x; vs[kb +  5][lb] = v1.y;
        vs[kb +  6][lb] = v1.z; vs[kb +  7][lb] = v1.w;
        vs[kb +  8][lb] = v2.x; vs[kb +  9][lb] = v2.y;
        vs[kb + 10][lb] = v2.z; vs[kb + 11][lb] = v2.w;
        vs[kb + 12][lb] = v3.x; vs[kb + 13][lb] = v3.y;
        vs[kb + 14][lb] = v3.z; vs[kb + 15][lb] = v3.w;
        ms[rk][ 0 + rg] = mv.x;  // j0+0, gate rg
        ms[rk][ 4 + rg] = mv.y;  // j0+1
        ms[rk][ 8 + rg] = mv.z;  // j0+2
        ms[rk][12 + rg] = mv.w;  // j0+3
        __syncthreads();
        #pragma unroll
        for (int kk = 0; kk < 64; ++kk) {
            float hv = vs[kk][b];
            float4 r = *(const float4*)&ms[kk][jj * 4];
            a0 = fmaf(hv, r.x, a0);
            a1 = fmaf(hv, r.y, a1);
            a2 = fmaf(hv, r.z, a2);
            a3 = fmaf(hv, r.w, a3);
        }
    }
}

__global__ __launch_bounds__(256)
void lstm_step(const float* __restrict__ wx_t,   // [64][4096] or nullptr (no-ws fallback)
               const float* __restrict__ x_t,    // [64][1024]
               const float* __restrict__ W,      // [1024][4096]
               const float* __restrict__ bias,   // [4096]
               const float* __restrict__ h_prev, // [64][1024] or nullptr (t==0)
               const float* __restrict__ R,      // [1024][4096]
               float* __restrict__ h_out,        // [64][1024]
               float* __restrict__ c_st)         // [64][1024]
{
    __shared__ float vs[64][66];
    __shared__ float ms[64][20];

    const int tid = threadIdx.x;
    const int b   = tid & 63;
    const int jj  = tid >> 6;
    const int j0  = blockIdx.x * 4;
    const int j   = j0 + jj;

    float a0 = 0.f, a1 = 0.f, a2 = 0.f, a3 = 0.f;

    if (!wx_t) {  // workspace too small: fuse x@W into the step
        accum_tile(x_t, W, j0, tid, b, jj, vs, ms, a0, a1, a2, a3);
        a0 += bias[j];
        a1 += bias[1024 + j];
        a2 += bias[2048 + j];
        a3 += bias[3072 + j];
    }
    if (h_prev)
        accum_tile(h_prev, R, j0, tid, b, jj, vs, ms, a0, a1, a2, a3);
    if (wx_t) {
        const float* wr = wx_t + (size_t)b * 4096 + j;
        a0 += wr[0];
        a1 += wr[1024];
        a2 += wr[2048];
        a3 += wr[3072];
    }

    const float ig = sigmoidf_(a0);
    const float gg = tanhf(a1);
    const float fg = sigmoidf_(a2);
    const float og = sigmoidf_(a3);
    const float cp = h_prev ? c_st[(size_t)b * 1024 + j] : 0.0f;
    const float cn = fg * cp + ig * gg;
    const float hn = og * tanhf(cn);
    c_st[(size_t)b * 1024 + j] = cn;

    // stage h through LDS so the global write is float4-coalesced per row
    __syncthreads();
    ((float*)vs)[b * 4 + jj] = hn;
    __syncthreads();
    if (tid < 64) {
        float4 v = *(const float4*)&((float*)vs)[tid * 4];
        *(float4*)&h_out[(size_t)tid * 1024 + j0] = v;
    }
}

// ---------------------------------------------------------------------------
// Tail: h_last = out[T-1], c_last = c  (each 64*1024 floats)
// ---------------------------------------------------------------------------
__global__ __launch_bounds__(256)
void finalize(float* __restrict__ out, const float* __restrict__ c)
{
    const int i = blockIdx.x * 256 + threadIdx.x;   // 0..65535
    const size_t TBH = (size_t)T_STEPS * B_SZ * H_SZ;
    const size_t BH  = (size_t)B_SZ * H_SZ;
    out[TBH + i]      = out[TBH - BH + i];
    out[TBH + BH + i] = c[i];
}

// ---------------------------------------------------------------------------
extern "C" void kernel_launch(void* const* d_in, const int* in_sizes, int n_in,
                              void* d_out, int out_size, void* d_ws, size_t ws_size,
                              hipStream_t stream)
{
    const float* x    = (const float*)d_in[0];  // [512,64,1024]
    const float* W    = (const float*)d_in[1];  // [1024,4096]
    const float* R    = (const float*)d_in[2];  // [1024,4096]
    const float* bias = (const float*)d_in[3];  // [4096]
    float* out = (float*)d_out;

    const size_t wx_elems = (size_t)T_STEPS * B_SZ * 4096;
    const bool have_ws = ws_size >= (wx_elems + (size_t)B_SZ * H_SZ) * sizeof(float);

    float* wx = (float*)d_ws;
    float* c  = have_ws ? (float*)d_ws + wx_elems : (float*)d_ws;

    if (have_ws) {
        dim3 grid(4096 / BN, (T_STEPS * B_SZ) / BM);
        wx_gemm<<<grid, 256, 0, stream>>>(x, W, bias, wx);
    }

    for (int t = 0; t < T_STEPS; ++t) {
        const float* wx_t = have_ws ? wx + (size_t)t * B_SZ * 4096 : nullptr;
        const float* x_t  = x + (size_t)t * B_SZ * I_SZ;
        const float* hp   = t ? out + (size_t)(t - 1) * B_SZ * H_SZ : nullptr;
        lstm_step<<<256, 256, 0, stream>>>(wx_t, x_t, W, bias, hp, R,
                                           out + (size_t)t * B_SZ * H_SZ, c);
    }

    finalize<<<256, 256, 0, stream>>>(out, c);
}

// Round 2
// 21702.048 us; speedup vs baseline: 1.0064x; 1.0064x over previous
//
#include <hip/hip_runtime.h>
#include <math.h>

#define T_STEPS 512
#define B_SZ    64
#define I_SZ    1024
#define H_SZ    1024
// N4 = 4*H = 4096

__device__ __forceinline__ float sigmoidf_(float x) { return 1.0f / (1.0f + expf(-x)); }

// bf16 helpers (DIY to avoid header-type/rounding ambiguity). RNE.
__device__ __forceinline__ short f2bf(float x) {
    unsigned u = __float_as_uint(x);
    unsigned r = (u + 0x7FFFu + ((u >> 16) & 1u)) >> 16;
    return (short)r;
}
__device__ __forceinline__ float bf2f(short s) {
    return __uint_as_float(((unsigned)(unsigned short)s) << 16);
}

typedef __attribute__((ext_vector_type(8))) short bf16x8;  // 8 bf16 = 4 VGPR
typedef __attribute__((ext_vector_type(4))) float f32x4;

// ---------------------------------------------------------------------------
// Phase 1: wx[m][n] = X[m][k] @ W[k][n] + bias[n]   (M=32768, N=4096, K=1024)
// fp32 vector GEMM, BM=64 BN=128 BK=16, 256 thr, 4x8 per thread. (known-good)
// ---------------------------------------------------------------------------
#define BM 64
#define BN 128
#define BK 16

__global__ __launch_bounds__(256)
void wx_gemm(const float* __restrict__ X, const float* __restrict__ W,
             const float* __restrict__ bias, float* __restrict__ wx)
{
    __shared__ float As[BK][BM + 4];
    __shared__ float Bs[BK][BN];

    const int tid = threadIdx.x;
    const int tx  = tid & 15;
    const int ty  = tid >> 4;
    const int m0  = blockIdx.y * BM;
    const int n0  = blockIdx.x * BN;

    float acc[4][8] = {};

    const int arow = tid >> 2;
    const int ak   = (tid & 3) * 4;
    const int brow = tid >> 5;
    const int bcol = (tid & 31) * 4;

    const float* Ag = X + (size_t)(m0 + arow) * I_SZ + ak;
    const float* Bg = W + (size_t)brow * 4096 + n0 + bcol;

    for (int k0 = 0; k0 < I_SZ; k0 += BK) {
        float4 av  = *(const float4*)(Ag + k0);
        float4 bv0 = *(const float4*)(Bg + (size_t)k0 * 4096);
        float4 bv1 = *(const float4*)(Bg + (size_t)(k0 + 8) * 4096);
        __syncthreads();
        As[ak + 0][arow] = av.x;
        As[ak + 1][arow] = av.y;
        As[ak + 2][arow] = av.z;
        As[ak + 3][arow] = av.w;
        *(float4*)&Bs[brow][bcol]     = bv0;
        *(float4*)&Bs[brow + 8][bcol] = bv1;
        __syncthreads();
        #pragma unroll
        for (int kk = 0; kk < BK; ++kk) {
            float4 a  = *(const float4*)&As[kk][ty * 4];
            float4 b0 = *(const float4*)&Bs[kk][tx * 8];
            float4 b1 = *(const float4*)&Bs[kk][tx * 8 + 4];
            float aa[4] = {a.x, a.y, a.z, a.w};
            float bb[8] = {b0.x, b0.y, b0.z, b0.w, b1.x, b1.y, b1.z, b1.w};
            #pragma unroll
            for (int i = 0; i < 4; ++i)
                #pragma unroll
                for (int jn = 0; jn < 8; ++jn)
                    acc[i][jn] = fmaf(aa[i], bb[jn], acc[i][jn]);
        }
    }

    float4 bi0 = *(const float4*)(bias + n0 + tx * 8);
    float4 bi1 = *(const float4*)(bias + n0 + tx * 8 + 4);
    float bb[8] = {bi0.x, bi0.y, bi0.z, bi0.w, bi1.x, bi1.y, bi1.z, bi1.w};
    #pragma unroll
    for (int i = 0; i < 4; ++i) {
        float* orow = wx + (size_t)(m0 + ty * 4 + i) * 4096 + n0 + tx * 8;
        float4 s0 = make_float4(acc[i][0] + bb[0], acc[i][1] + bb[1],
                                acc[i][2] + bb[2], acc[i][3] + bb[3]);
        float4 s1 = make_float4(acc[i][4] + bb[4], acc[i][5] + bb[5],
                                acc[i][6] + bb[6], acc[i][7] + bb[7]);
        *(float4*)orow       = s0;
        *(float4*)(orow + 4) = s1;
    }
}

// ---------------------------------------------------------------------------
// Prep: R[1024][4096] fp32 -> RT{h,m,l}[4096 n][1024 k] bf16 (exact 3-way split)
// 64x64 tile transpose through LDS. grid (64, 16), 256 thr.
// ---------------------------------------------------------------------------
__global__ __launch_bounds__(256)
void split_transpose_R(const float* __restrict__ R, short* __restrict__ Rh,
                       short* __restrict__ Rm, short* __restrict__ Rl)
{
    __shared__ float tile[64][65];
    const int tid = threadIdx.x;
    const int n0 = blockIdx.x * 64;
    const int k0 = blockIdx.y * 64;

    #pragma unroll
    for (int i = 0; i < 16; ++i) {
        int kl = i * 4 + (tid >> 6);
        tile[kl][tid & 63] = R[(size_t)(k0 + kl) * 4096 + n0 + (tid & 63)];
    }
    __syncthreads();
    #pragma unroll
    for (int i = 0; i < 16; ++i) {
        int nl = i * 4 + (tid >> 6);
        int kl = tid & 63;
        float v = tile[kl][nl];
        short sh = f2bf(v);
        float r1 = v - bf2f(sh);
        short sm = f2bf(r1);
        float r2 = r1 - bf2f(sm);
        short sl = f2bf(r2);
        size_t o = (size_t)(n0 + nl) * 1024 + k0 + kl;
        Rh[o] = sh; Rm[o] = sm; Rl[o] = sl;
    }
}

// ---------------------------------------------------------------------------
// Persistent scan: 256 blocks x 512 threads, one grid-wide barrier per step.
// Block = (jg = blk&63 -> 16 H-cols, mt = blk>>6 -> 16 batches). blk%8 = jg%8
// so all 4 m-blocks sharing an R slice land on the same XCD (L2-resident R).
// Wave w (8) = K-split slice of 128; 4 n-tiles (gates) x 6 split-MFMAs.
// h exchanged via global bf16 hi/mid/lo ping-pong planes (exact fp32 split).
// c lives in registers of epilogue threads. One atomic barrier per step.
// ---------------------------------------------------------------------------
__global__ __launch_bounds__(512, 2)
void lstm_scan(const float* __restrict__ wx,
               const short* __restrict__ Rh, const short* __restrict__ Rm,
               const short* __restrict__ Rl,
               short* hb,                      // [2 ping][3 comp][64*1024]
               float* __restrict__ out,        // [T][64][1024] + h_last + c_last
               unsigned int* bar)
{
    __shared__ float red[8][4][16][16];        // [wave][gate][m16][n16] 32KB

    const int tid  = threadIdx.x;
    const int w    = tid >> 6;
    const int lane = tid & 63;
    const int jg   = blockIdx.x & 63;
    const int mt   = blockIdx.x >> 6;
    const int b0   = mt * 16;
    const int j0   = jg * 16;
    const int frow = lane & 15;                // A's m-offset / B's n-offset / D's col
    const int quad = lane >> 4;
    const int kbase = w * 128 + quad * 8;

    const int m16 = tid >> 4;                  // epilogue (b,j) owner, tid<256
    const int n16 = tid & 15;
    float c_state = 0.0f;

    const size_t PLANE = 65536;                // 64*1024 bf16 elems

    #pragma unroll 1
    for (int t = 0; t < T_STEPS; ++t) {
        const int pr = t & 1, pw = (t + 1) & 1;

        // epilogue operand prefetch (independent of MFMA work)
        float wxv0 = 0.f, wxv1 = 0.f, wxv2 = 0.f, wxv3 = 0.f;
        if (tid < 256) {
            const float* wp = wx + (size_t)t * 262144 + (size_t)(b0 + m16) * 4096 + j0 + n16;
            wxv0 = wp[0]; wxv1 = wp[1024]; wxv2 = wp[2048]; wxv3 = wp[3072];
        }

        f32x4 acc0 = {0,0,0,0}, acc1 = {0,0,0,0}, acc2 = {0,0,0,0}, acc3 = {0,0,0,0};
        if (t > 0) {
            const short* hp = hb + (size_t)pr * 3 * PLANE + (size_t)(b0 + frow) * 1024;
            #pragma unroll
            for (int ki = 0; ki < 4; ++ki) {
                const int ko = kbase + ki * 32;
                bf16x8 ah = *(const bf16x8*)(hp + 0 * PLANE + ko);
                bf16x8 am = *(const bf16x8*)(hp + 1 * PLANE + ko);
                bf16x8 al = *(const bf16x8*)(hp + 2 * PLANE + ko);
                #pragma unroll
                for (int nt = 0; nt < 4; ++nt) {
                    const size_t ro = (size_t)(nt * 1024 + j0 + frow) * 1024 + ko;
                    bf16x8 bh = *(const bf16x8*)(Rh + ro);
                    bf16x8 bm = *(const bf16x8*)(Rm + ro);
                    bf16x8 bl = *(const bf16x8*)(Rl + ro);
                    f32x4 a = (nt == 0) ? acc0 : (nt == 1) ? acc1 : (nt == 2) ? acc2 : acc3;
                    a = __builtin_amdgcn_mfma_f32_16x16x32_bf16(ah, bh, a, 0, 0, 0);
                    a = __builtin_amdgcn_mfma_f32_16x16x32_bf16(ah, bm, a, 0, 0, 0);
                    a = __builtin_amdgcn_mfma_f32_16x16x32_bf16(am, bh, a, 0, 0, 0);
                    a = __builtin_amdgcn_mfma_f32_16x16x32_bf16(ah, bl, a, 0, 0, 0);
                    a = __builtin_amdgcn_mfma_f32_16x16x32_bf16(al, bh, a, 0, 0, 0);
                    a = __builtin_amdgcn_mfma_f32_16x16x32_bf16(am, bm, a, 0, 0, 0);
                    if (nt == 0) acc0 = a; else if (nt == 1) acc1 = a;
                    else if (nt == 2) acc2 = a; else acc3 = a;
                }
            }
        }

        // D layout: col = lane&15 (= n), row = quad*4 + r (= m)
        #pragma unroll
        for (int r = 0; r < 4; ++r) {
            red[w][0][quad * 4 + r][frow] = acc0[r];
            red[w][1][quad * 4 + r][frow] = acc1[r];
            red[w][2][quad * 4 + r][frow] = acc2[r];
            red[w][3][quad * 4 + r][frow] = acc3[r];
        }
        __syncthreads();

        if (tid < 256) {
            float P0 = wxv0, P1 = wxv1, P2 = wxv2, P3 = wxv3;
            #pragma unroll
            for (int ww = 0; ww < 8; ++ww) {
                P0 += red[ww][0][m16][n16];
                P1 += red[ww][1][m16][n16];
                P2 += red[ww][2][m16][n16];
                P3 += red[ww][3][m16][n16];
            }
            const float ig = sigmoidf_(P0);
            const float gg = tanhf(P1);
            const float fg = sigmoidf_(P2);
            const float og = sigmoidf_(P3);
            c_state = fg * c_state + ig * gg;
            const float hn = og * tanhf(c_state);

            const size_t oidx = (size_t)(b0 + m16) * 1024 + (j0 + n16);
            out[(size_t)t * 65536 + oidx] = hn;

            short* hw = hb + (size_t)pw * 3 * PLANE + oidx;
            short s0 = f2bf(hn);
            float r1 = hn - bf2f(s0);
            short s1 = f2bf(r1);
            float r2 = r1 - bf2f(s1);
            short s2 = f2bf(r2);
            hw[0 * PLANE] = s0; hw[1 * PLANE] = s1; hw[2 * PLANE] = s2;

            if (t == T_STEPS - 1) {
                out[33554432 + oidx]         = hn;       // h_last
                out[33554432 + 65536 + oidx] = c_state;  // c_last
            }
        }

        // publish h_t device-wide, then grid barrier
        __threadfence();
        __syncthreads();
        if (tid == 0) {
            __hip_atomic_fetch_add(bar, 1u, __ATOMIC_RELEASE, __HIP_MEMORY_SCOPE_AGENT);
            const unsigned target = 256u * (unsigned)(t + 1);
            while (__hip_atomic_load(bar, __ATOMIC_ACQUIRE, __HIP_MEMORY_SCOPE_AGENT) < target)
                __builtin_amdgcn_s_sleep(2);
        }
        __syncthreads();
    }
}

// ---------------------------------------------------------------------------
// Legacy round-1 fallback path (used only if ws too small for the new layout)
// ---------------------------------------------------------------------------
__device__ __forceinline__ void accum_tile(
    const float* __restrict__ vec, const float* __restrict__ mat,
    int j0, int tid, int b, int jj,
    float (&vs)[64][66], float (&ms)[64][20],
    float& a0, float& a1, float& a2, float& a3)
{
    const int lb  = tid & 63;
    const int lkq = tid >> 6;
    const int rk  = tid & 63;
    const int rg  = tid >> 6;

    const float* Vg = vec + (size_t)lb * 1024 + lkq * 16;
    const float* Mg = mat + (size_t)rk * 4096 + (size_t)rg * 1024 + j0;

    for (int k0 = 0; k0 < 1024; k0 += 64) {
        float4 v0 = *(const float4*)(Vg + k0 + 0);
        float4 v1 = *(const float4*)(Vg + k0 + 4);
        float4 v2 = *(const float4*)(Vg + k0 + 8);
        float4 v3 = *(const float4*)(Vg + k0 + 12);
        float4 mv = *(const float4*)(Mg + (size_t)k0 * 4096);
        __syncthreads();
        const int kb = lkq * 16;
        vs[kb +  0][lb] = v0.x; vs[kb +  1][lb] = v0.y;
        vs[kb +  2][lb] = v0.z; vs[kb +  3][lb] = v0.w;
        vs[kb +  4][lb] = v1.x; vs[kb +  5][lb] = v1.y;
        vs[kb +  6][lb] = v1.z; vs[kb +  7][lb] = v1.w;
        vs[kb +  8][lb] = v2.x; vs[kb +  9][lb] = v2.y;
        vs[kb + 10][lb] = v2.z; vs[kb + 11][lb] = v2.w;
        vs[kb + 12][lb] = v3.x; vs[kb + 13][lb] = v3.y;
        vs[kb + 14][lb] = v3.z; vs[kb + 15][lb] = v3.w;
        ms[rk][ 0 + rg] = mv.x;
        ms[rk][ 4 + rg] = mv.y;
        ms[rk][ 8 + rg] = mv.z;
        ms[rk][12 + rg] = mv.w;
        __syncthreads();
        #pragma unroll
        for (int kk = 0; kk < 64; ++kk) {
            float hv = vs[kk][b];
            float4 r = *(const float4*)&ms[kk][jj * 4];
            a0 = fmaf(hv, r.x, a0);
            a1 = fmaf(hv, r.y, a1);
            a2 = fmaf(hv, r.z, a2);
            a3 = fmaf(hv, r.w, a3);
        }
    }
}

__global__ __launch_bounds__(256)
void lstm_step(const float* __restrict__ wx_t, const float* __restrict__ x_t,
               const float* __restrict__ W, const float* __restrict__ bias,
               const float* __restrict__ h_prev, const float* __restrict__ R,
               float* __restrict__ h_out, float* __restrict__ c_st)
{
    __shared__ float vs[64][66];
    __shared__ float ms[64][20];

    const int tid = threadIdx.x;
    const int b   = tid & 63;
    const int jj  = tid >> 6;
    const int j0  = blockIdx.x * 4;
    const int j   = j0 + jj;

    float a0 = 0.f, a1 = 0.f, a2 = 0.f, a3 = 0.f;

    if (!wx_t) {
        accum_tile(x_t, W, j0, tid, b, jj, vs, ms, a0, a1, a2, a3);
        a0 += bias[j];
        a1 += bias[1024 + j];
        a2 += bias[2048 + j];
        a3 += bias[3072 + j];
    }
    if (h_prev)
        accum_tile(h_prev, R, j0, tid, b, jj, vs, ms, a0, a1, a2, a3);
    if (wx_t) {
        const float* wr = wx_t + (size_t)b * 4096 + j;
        a0 += wr[0];
        a1 += wr[1024];
        a2 += wr[2048];
        a3 += wr[3072];
    }

    const float ig = sigmoidf_(a0);
    const float gg = tanhf(a1);
    const float fg = sigmoidf_(a2);
    const float og = sigmoidf_(a3);
    const float cp = h_prev ? c_st[(size_t)b * 1024 + j] : 0.0f;
    const float cn = fg * cp + ig * gg;
    const float hn = og * tanhf(cn);
    c_st[(size_t)b * 1024 + j] = cn;

    __syncthreads();
    ((float*)vs)[b * 4 + jj] = hn;
    __syncthreads();
    if (tid < 64) {
        float4 v = *(const float4*)&((float*)vs)[tid * 4];
        *(float4*)&h_out[(size_t)tid * 1024 + j0] = v;
    }
}

__global__ __launch_bounds__(256)
void finalize(float* __restrict__ out, const float* __restrict__ c)
{
    const int i = blockIdx.x * 256 + threadIdx.x;
    const size_t TBH = (size_t)T_STEPS * B_SZ * H_SZ;
    const size_t BH  = (size_t)B_SZ * H_SZ;
    out[TBH + i]      = out[TBH - BH + i];
    out[TBH + BH + i] = c[i];
}

// ---------------------------------------------------------------------------
extern "C" void kernel_launch(void* const* d_in, const int* in_sizes, int n_in,
                              void* d_out, int out_size, void* d_ws, size_t ws_size,
                              hipStream_t stream)
{
    const float* x    = (const float*)d_in[0];  // [512,64,1024]
    const float* W    = (const float*)d_in[1];  // [1024,4096]
    const float* R    = (const float*)d_in[2];  // [1024,4096]
    const float* bias = (const float*)d_in[3];  // [4096]
    float* out = (float*)d_out;

    // ws layout (new path):
    //   bar   @ 0        (256 B)
    //   hb    @ 256      (2*3*65536*2 = 786432 B)
    //   RTh/m/l @ 786688 (3 * 8388608 B)
    //   wx    @ 25952512 (512 MB)
    const size_t OFF_HB = 256;
    const size_t OFF_RT = 786688;
    const size_t OFF_WX = 25952512;
    const size_t NEED_NEW = OFF_WX + (size_t)T_STEPS * B_SZ * 4096 * sizeof(float);

    if (ws_size >= NEED_NEW) {
        unsigned int* bar = (unsigned int*)d_ws;
        short* hb  = (short*)((char*)d_ws + OFF_HB);
        short* RTh = (short*)((char*)d_ws + OFF_RT);
        short* RTm = (short*)((char*)d_ws + OFF_RT + 8388608);
        short* RTl = (short*)((char*)d_ws + OFF_RT + 16777216);
        float* wx  = (float*)((char*)d_ws + OFF_WX);

        hipMemsetAsync(d_ws, 0, 256, stream);

        dim3 tg(64, 16);
        split_transpose_R<<<tg, 256, 0, stream>>>(R, RTh, RTm, RTl);

        dim3 grid(4096 / BN, (T_STEPS * B_SZ) / BM);
        wx_gemm<<<grid, 256, 0, stream>>>(x, W, bias, wx);

        lstm_scan<<<256, 512, 0, stream>>>(wx, RTh, RTm, RTl, hb, out, bar);
        return;
    }

    // legacy fallback
    const size_t wx_elems = (size_t)T_STEPS * B_SZ * 4096;
    const bool have_ws = ws_size >= (wx_elems + (size_t)B_SZ * H_SZ) * sizeof(float);
    float* wx = (float*)d_ws;
    float* c  = have_ws ? (float*)d_ws + wx_elems : (float*)d_ws;

    if (have_ws) {
        dim3 grid(4096 / BN, (T_STEPS * B_SZ) / BM);
        wx_gemm<<<grid, 256, 0, stream>>>(x, W, bias, wx);
    }
    for (int t = 0; t < T_STEPS; ++t) {
        const float* wx_t = have_ws ? wx + (size_t)t * B_SZ * 4096 : nullptr;
        const float* x_t  = x + (size_t)t * B_SZ * I_SZ;
        const float* hp   = t ? out + (size_t)(t - 1) * B_SZ * H_SZ : nullptr;
        lstm_step<<<256, 256, 0, stream>>>(wx_t, x_t, W, bias, hp, R,
                                           out + (size_t)t * B_SZ * H_SZ, c);
    }
    finalize<<<256, 256, 0, stream>>>(out, c);
}